// Round 12
// baseline (17.380 us; speedup 1.0000x reference)
//
#include <hip/hip_runtime.h>

#define DEV __device__ __forceinline__

namespace {

typedef float f32x2 __attribute__((ext_vector_type(2)));

DEV f32x2 splat(float x){ f32x2 r; r.x = x; r.y = x; return r; }
DEV f32x2 csw(f32x2 a){ return __builtin_shufflevector(a, a, 1, 0); }
DEV f32x2 cmulv(f32x2 a, f32x2 b){
  f32x2 nt; nt.x = -b.y; nt.y = b.x;
  return splat(a.x)*b + splat(a.y)*nt;
}
DEV f32x2 cconj(f32x2 a){ a.y = -a.y; return a; }
// a * e^{i phi} from scalar (c,s)
DEV f32x2 cphase2(f32x2 a, float c, float s){
  f32x2 sv; sv.x = -s; sv.y = s;
  return splat(c)*a + sv*csw(a);
}
DEV void halfsc(float th, float& c, float& s){ __sincosf(0.5f*th, &s, &c); }

constexpr float RSQRT2 = 0.70710678118654752440f;
constexpr float PI_F   = 3.14159265358979323846f;

// in-wave LDS ordering: lockstep wave + drained lgkm queue; no barrier needed
DEV void wave_lds_fence(){ asm volatile("s_waitcnt lgkmcnt(0)" ::: "memory"); }

// ---- cross-lane xor exchange within aligned 16-lane groups ----------------
template<int CTRL> DEV float qperm(float v){
  return __int_as_float(__builtin_amdgcn_mov_dpp(__float_as_int(v), CTRL, 0xF, 0xF, true));
}
template<int OFF> DEV float swzf(float v){
  return __int_as_float(__builtin_amdgcn_ds_swizzle(__float_as_int(v), OFF));
}
template<int B> DEV float shfx(float v){
  if constexpr (B==1)      return qperm<0xB1>(v);      // quad_perm [1,0,3,2]
  else if constexpr (B==2) return qperm<0x4E>(v);      // quad_perm [2,3,0,1]
  else if constexpr (B==4) return swzf<0x101F>(v);     // xor 4 (BitMode)
  else                     return qperm<0x128>(v);     // row_ror:8 == xor 8
}

// ---- gate chain runner: gates I0..I0+N-1; even index = RZ, odd = RX -------
template<int I0, int N> DEV void run_gates(f32x2 (&v)[2], const float* f, float scale){
  #pragma unroll
  for (int i = I0; i < I0 + N; ++i){
    float c, s; halfsc(scale * f[i], c, s);
    f32x2 cv = splat(c);
    f32x2 sp; sp.x = s;  sp.y = -s;
    if ((i & 1) == 0){                     // RZ
      f32x2 sn; sn.x = -s; sn.y = s;
      v[0] = cv*v[0] + sp*csw(v[0]);
      v[1] = cv*v[1] + sn*csw(v[1]);
    } else {                               // RX
      f32x2 t0 = csw(v[0]), t1 = csw(v[1]);
      v[0] = cv*v[0] + sp*t1;
      v[1] = cv*v[1] + sp*t0;
    }
  }
}
template<int N> DEV void build_psi(f32x2 (&v)[2], const float* ang, float scale){
  v[0].x = RSQRT2; v[0].y = 0.f;
  v[1].x = RSQRT2; v[1].y = 0.f;
  run_gates<0, N>(v, ang, scale);
}

// ---- gates on a 16-amp register state (packed) ----------------------------
template<int S> DEV void ry_loc16(f32x2 (&a)[16], float2 cs){
  const float c = cs.x, s = cs.y;
  #pragma unroll
  for (int m = 0; m < 16; ++m) if (!(m & S)) {
    f32x2 u = a[m], v = a[m|S];
    a[m]   = splat(c)*u - splat(s)*v;
    a[m|S] = splat(s)*u + splat(c)*v;
  }
}
template<int MASK> DEV void ry_lane16(f32x2 (&a)[16], int r, float2 cs){
  const float c = cs.x;
  const float sg = (r & MASK) ? cs.y : -cs.y;
  #pragma unroll
  for (int m = 0; m < 16; ++m){
    f32x2 o; o.x = shfx<MASK>(a[m].x); o.y = shfx<MASK>(a[m].y);
    a[m] = splat(c)*a[m] + splat(sg)*o;
  }
}

DEV f32x2 tov(float2 v){ f32x2 r; r.x = v.x; r.y = v.y; return r; }

} // namespace

// 16 samples x 16 lanes per 256-thread block; thread-local ph1 chains,
// wave-local ph2 dataflow, ONE barrier (weight tables)
__global__ __launch_bounds__(256, 2)
void qnn_fused_kernel(const float* __restrict__ X,  const float* __restrict__ w1,
                      const float* __restrict__ w2, const float* __restrict__ fcw,
                      const float* __restrict__ fcb, float* __restrict__ out, int bs)
{
  __shared__ float  feats[16][80];          // [64..79] zero pad for chain 7
  __shared__ float4 chainH[16][8][2];       // phase-2 chain halves
  __shared__ float4 chain2[16][9];          // phase-2 chains, pad 9
  __shared__ float2 p1phi2[2][16];          // phase-1 merged-CRZ (c,s)
  __shared__ float2 p1ry[2][4];             // phase-1 RY (c,s) half-angle
  __shared__ float2 ryw[3][8];              // phase-2 RY (c,s) half-angle
  __shared__ float2 phi2[3*16*18];          // phase-2 merged-CRZ, row stride 18

  const int t  = threadIdx.x;
  const int wv = t >> 6;                    // wave 0..3 (owns samples 4wv..4wv+3)
  const int ln = t & 63;                    // lane in wave
  const int sl = t >> 4;                    // local sample 0..15
  const int r  = t & 15;                    // lane id in group: patch (ph1) / wire bits (ph2)
  int sample = blockIdx.x * 16 + sl;
  if (sample >= bs) sample = bs - 1;

  // ---------------- weight tables (block-shared) ---------------------------
  if (t < 32){                              // p1phi2: l=t>>4, m=t&15
    const int l = t >> 4, m = t & 15;
    const float h0 = 0.5f*w1[l*8+0], h1 = 0.5f*w1[l*8+1];
    const float h2 = 0.5f*w1[l*8+2], h3 = 0.5f*w1[l*8+3];
    const bool b0 = m & 8, b1 = m & 4, b2 = m & 2, b3 = m & 1;
    float phi = 0.f;
    phi += b0 ? (b1 ? h0 : -h0) : 0.f;      // CRZ(w0,w1)
    phi += b1 ? (b2 ? h1 : -h1) : 0.f;      // CRZ(w1,w2)
    phi += b2 ? (b3 ? h2 : -h2) : 0.f;      // CRZ(w2,w3)
    phi += b3 ? (b0 ? h3 : -h3) : 0.f;      // CRZ(w3,w0)
    float c, s; __sincosf(phi, &s, &c);
    p1phi2[l][m] = {c, s};
  } else if (t < 40){
    const int j = t - 32, l = j >> 2, i = j & 3;
    float c, s; halfsc(w1[l*8 + 4 + i], c, s); p1ry[l][i] = {c, s};
  } else if (t < 64){
    const int j = t - 40, l = j >> 3, i = j & 7;
    float c, s; halfsc(w2[l*16 + 8 + i], c, s); ryw[l][i] = {c, s};
  }
  #pragma unroll
  for (int jj = 0; jj < 3; ++jj){           // phi2: 768 jobs
    const int idx = t + jj*256;
    const int l = idx >> 8, rr = (idx >> 4) & 15, mm = idx & 15;
    const float* wl = w2 + l*16;
    float h[8];
    #pragma unroll
    for (int i = 0; i < 8; ++i) h[i] = 0.5f*wl[i];
    bool b[8];
    b[0]=(rr>>3)&1; b[1]=(rr>>2)&1; b[2]=(rr>>1)&1; b[3]=rr&1;     // lane wires
    b[4]=(mm>>3)&1; b[5]=(mm>>2)&1; b[6]=(mm>>1)&1; b[7]=mm&1;     // local wires
    float phi = 0.f;
    #pragma unroll
    for (int i = 0; i < 8; ++i)
      phi += b[i] ? (b[(i+1)&7] ? h[i] : -h[i]) : 0.f;
    float c, s; __sincosf(phi, &s, &c);
    phi2[(l*16 + rr)*18 + mm] = {c, s};
  }

  // ------ phase-1 chains: THREAD-LOCAL (lane r = patch r), no LDS ----------
  f32x2 ps[4][2];
  {
    const int pi = r >> 2, pj = r & 3;
    const int shift = (pj == 3) ? 1 : 2;
    const int cmask = (1 << shift) - 1;
    const int limit = ((pi == 3) ? 2 : 4) << shift;
    const float* Xf = X + (size_t)sample * 196;  // L1/L2-resident
    float px[16];
    #pragma unroll
    for (int k = 0; k < 16; ++k){
      int idx = (pi*4 + (k >> shift))*14 + pj*4 + (k & cmask);
      idx = idx > 195 ? 195 : idx;
      float v = Xf[idx];
      px[k] = (k < limit) ? v : 0.f;        // RZ(0)/RX(0) == identity
    }
    #pragma unroll
    for (int q = 0; q < 4; ++q) build_psi<4>(ps[q], &px[q*4], 1.0f);
  }
  __syncthreads();                          // the ONLY barrier (tables ready)

  // ------- phase 1 evolution: patch r per lane, all 4 wires LOCAL ----------
  {
    f32x2 a[16];
    {
      f32x2 T01[4], T23[4];
      #pragma unroll
      for (int j = 0; j < 4; ++j){
        T01[j] = cmulv(ps[0][j>>1], ps[1][j&1]);
        T23[j] = cmulv(ps[2][j>>1], ps[3][j&1]);
      }
      #pragma unroll
      for (int m = 0; m < 16; ++m) a[m] = cmulv(T01[m>>2], T23[m&3]);
    }

    #pragma unroll
    for (int l = 0; l < 2; ++l){
      const float4* ph4 = (const float4*)&p1phi2[l][0];  // uniform broadcast
      #pragma unroll
      for (int j = 0; j < 8; ++j){
        float4 w = ph4[j];
        a[2*j]   = cphase2(a[2*j],   w.x, w.y);
        a[2*j+1] = cphase2(a[2*j+1], w.z, w.w);
      }
      ry_loc16<8>(a, p1ry[l][0]); ry_loc16<4>(a, p1ry[l][1]);
      ry_loc16<2>(a, p1ry[l][2]); ry_loc16<1>(a, p1ry[l][3]);
    }

    float pr[16];
    #pragma unroll
    for (int m = 0; m < 16; ++m) pr[m] = a[m].x*a[m].x + a[m].y*a[m].y;
    #pragma unroll
    for (int w = 0; w < 4; ++w){
      const int S = 8 >> w;
      float e = 0.f;
      #pragma unroll
      for (int m = 0; m < 16; ++m) e += (m & S) ? -pr[m] : pr[m];
      feats[sl][r*4 + w] = e;
    }
    feats[sl][64 + r] = 0.f;                // zero pad f[64..79]
  }
  wave_lds_fence();                         // wave-local: no barrier

  // ------ phase-2 chain halves: all 64 lanes busy, wave-local --------------
  // h=0 (lanes 0-31): state after H + gates 0..4 ; h=1 (lanes 32-63): SU(2)
  // (alpha,beta) of gates 5..8.
  {
    const int h = ln >> 5, idx = ln & 31;
    const int s_ = wv*4 + (idx >> 3), c = idx & 7;
    const float* f = &feats[s_][c*9];
    f32x2 v[2];
    if (h == 0){
      build_psi<5>(v, f, PI_F);             // H + gates 0..4
    } else {
      v[0].x = 1.f; v[0].y = 0.f;
      v[1].x = 0.f; v[1].y = 0.f;
      run_gates<5, 4>(v, f, PI_F);          // gates 5..8
    }
    chainH[s_][c][h] = {v[0].x, v[0].y, v[1].x, v[1].y};
  }
  wave_lds_fence();
  if (ln < 32){                             // combine: v = M_B * v_A
    const int s_ = wv*4 + (ln >> 3), c = ln & 7;
    float4 A = chainH[s_][c][0], B = chainH[s_][c][1];
    f32x2 vA0, vA1, al, be;
    vA0.x=A.x; vA0.y=A.y; vA1.x=A.z; vA1.y=A.w;
    al.x=B.x;  al.y=B.y;  be.x=B.z;  be.y=B.w;
    f32x2 v0 = cmulv(al, vA0) - cmulv(cconj(be), vA1);
    f32x2 v1 = cmulv(be, vA0) + cmulv(cconj(al), vA1);
    chain2[s_][c] = {v0.x, v0.y, v1.x, v1.y};
  }
  wave_lds_fence();                         // wave-local: no barrier

  // ------- assemble product state: lanes = wires 0-3, local = wires 4-7 ----
  f32x2 a[16];
  {
    const float2* c2 = (const float2*)&chain2[sl][0];
    f32x2 e0 = tov(c2[0*2 + ((r>>3)&1)]);
    f32x2 e1 = tov(c2[1*2 + ((r>>2)&1)]);
    f32x2 e2 = tov(c2[2*2 + ((r>>1)&1)]);
    f32x2 e3 = tov(c2[3*2 + ( r    &1)]);
    f32x2 L  = cmulv(cmulv(e0, e1), cmulv(e2, e3));

    float4 q4 = chain2[sl][4], q5 = chain2[sl][5];
    float4 q6 = chain2[sl][6], q7 = chain2[sl][7];
    f32x2 p4[2], p5[2], p6[2], p7[2];
    p4[0].x=q4.x; p4[0].y=q4.y; p4[1].x=q4.z; p4[1].y=q4.w;
    p5[0].x=q5.x; p5[0].y=q5.y; p5[1].x=q5.z; p5[1].y=q5.w;
    p6[0].x=q6.x; p6[0].y=q6.y; p6[1].x=q6.z; p6[1].y=q6.w;
    p7[0].x=q7.x; p7[0].y=q7.y; p7[1].x=q7.z; p7[1].y=q7.w;
    f32x2 p45[4], p67[4];
    #pragma unroll
    for (int j = 0; j < 4; ++j){
      p45[j] = cmulv(p4[j>>1], p5[j&1]);
      p67[j] = cmulv(p6[j>>1], p7[j&1]);
    }
    f32x2 Lp[4];
    #pragma unroll
    for (int j = 0; j < 4; ++j) Lp[j] = cmulv(L, p45[j]);
    #pragma unroll
    for (int m = 0; m < 16; ++m) a[m] = cmulv(Lp[m>>2], p67[m&3]);
  }

  // ---------------- 3 layers: table-CRZ ring + RY on wires 0..7 ------------
  #pragma unroll
  for (int l = 0; l < 3; ++l){
    const float4* ph4 = (const float4*)&phi2[(l*16 + r)*18];
    #pragma unroll
    for (int j = 0; j < 8; ++j){
      float4 w = ph4[j];
      a[2*j]   = cphase2(a[2*j],   w.x, w.y);
      a[2*j+1] = cphase2(a[2*j+1], w.z, w.w);
    }
    ry_lane16<8>(a, r, ryw[l][0]);          // wire0 (DPP row_ror:8)
    ry_lane16<4>(a, r, ryw[l][1]);          // wire1 (ds_swizzle — the only one)
    ry_lane16<2>(a, r, ryw[l][2]);          // wire2 (DPP quad)
    ry_lane16<1>(a, r, ryw[l][3]);          // wire3 (DPP quad)
    ry_loc16<8>(a, ryw[l][4]);              // wire4
    ry_loc16<4>(a, ryw[l][5]);              // wire5
    ry_loc16<2>(a, ryw[l][6]);              // wire6
    ry_loc16<1>(a, ryw[l][7]);              // wire7
  }

  // ---------------- measurement + FC ---------------------------------------
  float pr[16];
  #pragma unroll
  for (int m = 0; m < 16; ++m) pr[m] = a[m].x*a[m].x + a[m].y*a[m].y;
  float Ssum = 0.f;
  #pragma unroll
  for (int m = 0; m < 16; ++m) Ssum += pr[m];
  float gp[8];
  gp[0] = (r & 8) ? -Ssum : Ssum;
  gp[1] = (r & 4) ? -Ssum : Ssum;
  gp[2] = (r & 2) ? -Ssum : Ssum;
  gp[3] = (r & 1) ? -Ssum : Ssum;
  #pragma unroll
  for (int w = 4; w < 8; ++w){
    const int S = 8 >> (w-4);
    float e = 0.f;
    #pragma unroll
    for (int m = 0; m < 16; ++m) e += (m & S) ? -pr[m] : pr[m];
    gp[w] = e;
  }

  float o0 = 0.f, o1 = 0.f, o2 = 0.f;
  #pragma unroll
  for (int w = 0; w < 8; ++w){
    o0 += fcw[0*8 + w] * gp[w];
    o1 += fcw[1*8 + w] * gp[w];
    o2 += fcw[2*8 + w] * gp[w];
  }
  o0 += shfx<1>(o0); o1 += shfx<1>(o1); o2 += shfx<1>(o2);
  o0 += shfx<2>(o0); o1 += shfx<2>(o1); o2 += shfx<2>(o2);
  o0 += shfx<4>(o0); o1 += shfx<4>(o1); o2 += shfx<4>(o2);
  o0 += shfx<8>(o0); o1 += shfx<8>(o1); o2 += shfx<8>(o2);

  if (r < 3){
    float o = (r == 0) ? o0 : ((r == 1) ? o1 : o2);
    out[(size_t)sample*3 + r] = o + fcb[r];
  }
}

extern "C" void kernel_launch(void* const* d_in, const int* in_sizes, int n_in,
                              void* d_out, int out_size, void* d_ws, size_t ws_size,
                              hipStream_t stream)
{
  const float* X   = (const float*)d_in[0];
  const float* w1  = (const float*)d_in[1];
  const float* w2  = (const float*)d_in[2];
  const float* fcw = (const float*)d_in[3];
  const float* fcb = (const float*)d_in[4];
  float* out = (float*)d_out;
  const int bs = in_sizes[0] / 196;            // 8192
  const int blocks = (bs + 15) / 16;           // 16 samples / 256-thread block
  hipLaunchKernelGGL(qnn_fused_kernel, dim3(blocks), dim3(256), 0, stream,
                     X, w1, w2, fcw, fcb, out, bs);
}

// Round 13
// 17.011 us; speedup vs baseline: 1.0217x; 1.0217x over previous
//
#include <hip/hip_runtime.h>

#define DEV __device__ __forceinline__

namespace {

typedef float f32x2 __attribute__((ext_vector_type(2)));

DEV f32x2 splat(float x){ f32x2 r; r.x = x; r.y = x; return r; }
DEV f32x2 csw(f32x2 a){ return __builtin_shufflevector(a, a, 1, 0); }
DEV f32x2 cmulv(f32x2 a, f32x2 b){
  f32x2 nt; nt.x = -b.y; nt.y = b.x;
  return splat(a.x)*b + splat(a.y)*nt;
}
// a * e^{i phi} from scalar (c,s)
DEV f32x2 cphase2(f32x2 a, float c, float s){
  f32x2 sv; sv.x = -s; sv.y = s;
  return splat(c)*a + sv*csw(a);
}
DEV void halfsc(float th, float& c, float& s){ __sincosf(0.5f*th, &s, &c); }

constexpr float RSQRT2 = 0.70710678118654752440f;
constexpr float PI_F   = 3.14159265358979323846f;

// in-wave LDS ordering: lockstep wave + drained lgkm queue; no barrier needed
DEV void wave_lds_fence(){ asm volatile("s_waitcnt lgkmcnt(0)" ::: "memory"); }

// ---- cross-lane xor exchange within aligned 16-lane groups ----------------
// masks 1,2: DPP quad_perm; 8: DPP row_ror:8; 4: ds_swizzle (only LDS-pipe op)
template<int CTRL> DEV float qperm(float v){
  return __int_as_float(__builtin_amdgcn_mov_dpp(__float_as_int(v), CTRL, 0xF, 0xF, true));
}
template<int OFF> DEV float swzf(float v){
  return __int_as_float(__builtin_amdgcn_ds_swizzle(__float_as_int(v), OFF));
}
template<int B> DEV float shfx(float v){
  if constexpr (B==1)      return qperm<0xB1>(v);      // quad_perm [1,0,3,2]
  else if constexpr (B==2) return qperm<0x4E>(v);      // quad_perm [2,3,0,1]
  else if constexpr (B==4) return swzf<0x101F>(v);     // xor 4 (BitMode)
  else                     return qperm<0x128>(v);     // row_ror:8 == xor 8
}

// ---- gate chain runner: gates I0..I0+N-1; even index = RZ, odd = RX -------
template<int I0, int N> DEV void run_gates(f32x2 (&v)[2], const float* f, float scale){
  #pragma unroll
  for (int i = I0; i < I0 + N; ++i){
    float c, s; halfsc(scale * f[i], c, s);
    f32x2 cv = splat(c);
    f32x2 sp; sp.x = s;  sp.y = -s;
    if ((i & 1) == 0){                     // RZ
      f32x2 sn; sn.x = -s; sn.y = s;
      v[0] = cv*v[0] + sp*csw(v[0]);
      v[1] = cv*v[1] + sn*csw(v[1]);
    } else {                               // RX
      f32x2 t0 = csw(v[0]), t1 = csw(v[1]);
      v[0] = cv*v[0] + sp*t1;
      v[1] = cv*v[1] + sp*t0;
    }
  }
}
template<int N> DEV void build_psi(f32x2 (&v)[2], const float* ang, float scale){
  v[0].x = RSQRT2; v[0].y = 0.f;
  v[1].x = RSQRT2; v[1].y = 0.f;
  run_gates<0, N>(v, ang, scale);
}

// ---- gates on a 16-amp register state (packed) ----------------------------
template<int S> DEV void ry_loc16(f32x2 (&a)[16], float2 cs){
  const float c = cs.x, s = cs.y;
  #pragma unroll
  for (int m = 0; m < 16; ++m) if (!(m & S)) {
    f32x2 u = a[m], v = a[m|S];
    a[m]   = splat(c)*u - splat(s)*v;
    a[m|S] = splat(s)*u + splat(c)*v;
  }
}
template<int MASK> DEV void ry_lane16(f32x2 (&a)[16], int r, float2 cs){
  const float c = cs.x;
  const float sg = (r & MASK) ? cs.y : -cs.y;
  #pragma unroll
  for (int m = 0; m < 16; ++m){
    f32x2 o; o.x = shfx<MASK>(a[m].x); o.y = shfx<MASK>(a[m].y);
    a[m] = splat(c)*a[m] + splat(sg)*o;
  }
}

DEV f32x2 tov(float2 v){ f32x2 r; r.x = v.x; r.y = v.y; return r; }

} // namespace

// 16 samples x 16 lanes per 256-thread block; wave-local dataflow, 1 barrier
// (r11 structure — best measured: 17.02 us)
__global__ __launch_bounds__(256, 2)
void qnn_fused_kernel(const float* __restrict__ X,  const float* __restrict__ w1,
                      const float* __restrict__ w2, const float* __restrict__ fcw,
                      const float* __restrict__ fcb, float* __restrict__ out, int bs)
{
  __shared__ float  feats[16][80];          // [64..79] zero pad for chain 7
  __shared__ float4 p1chain[16][16][5];     // phase-1 chains, row pad 5
  __shared__ float4 chain2[16][9];          // phase-2 chains, pad 9
  __shared__ float2 p1phi2[2][16];          // phase-1 merged-CRZ (c,s)
  __shared__ float2 p1ry[2][4];             // phase-1 RY (c,s) half-angle
  __shared__ float2 ryw[3][8];              // phase-2 RY (c,s) half-angle
  __shared__ float2 phi2[3*16*18];          // phase-2 merged-CRZ, row stride 18

  const int t  = threadIdx.x;
  const int wv = t >> 6;                    // wave 0..3 (owns samples 4wv..4wv+3)
  const int ln = t & 63;                    // lane in wave
  const int sl = t >> 4;                    // local sample 0..15
  const int r  = t & 15;                    // lane id in sample group
  int sample = blockIdx.x * 16 + sl;
  if (sample >= bs) sample = bs - 1;

  // ---------------- weight tables (block-shared, one barrier) --------------
  if (t < 32){                              // p1phi2: l=t>>4, m=t&15
    const int l = t >> 4, m = t & 15;
    const float h0 = 0.5f*w1[l*8+0], h1 = 0.5f*w1[l*8+1];
    const float h2 = 0.5f*w1[l*8+2], h3 = 0.5f*w1[l*8+3];
    const bool b0 = m & 8, b1 = m & 4, b2 = m & 2, b3 = m & 1;
    float phi = 0.f;
    phi += b0 ? (b1 ? h0 : -h0) : 0.f;      // CRZ(w0,w1)
    phi += b1 ? (b2 ? h1 : -h1) : 0.f;      // CRZ(w1,w2)
    phi += b2 ? (b3 ? h2 : -h2) : 0.f;      // CRZ(w2,w3)
    phi += b3 ? (b0 ? h3 : -h3) : 0.f;      // CRZ(w3,w0)
    float c, s; __sincosf(phi, &s, &c);
    p1phi2[l][m] = {c, s};
  } else if (t < 40){
    const int j = t - 32, l = j >> 2, i = j & 3;
    float c, s; halfsc(w1[l*8 + 4 + i], c, s); p1ry[l][i] = {c, s};
  } else if (t < 64){
    const int j = t - 40, l = j >> 3, i = j & 7;
    float c, s; halfsc(w2[l*16 + 8 + i], c, s); ryw[l][i] = {c, s};
  }
  #pragma unroll
  for (int jj = 0; jj < 3; ++jj){           // phi2: 768 jobs
    const int idx = t + jj*256;
    const int l = idx >> 8, rr = (idx >> 4) & 15, mm = idx & 15;
    const float* wl = w2 + l*16;
    float h[8];
    #pragma unroll
    for (int i = 0; i < 8; ++i) h[i] = 0.5f*wl[i];
    bool b[8];
    b[0]=(rr>>3)&1; b[1]=(rr>>2)&1; b[2]=(rr>>1)&1; b[3]=rr&1;     // lane wires
    b[4]=(mm>>3)&1; b[5]=(mm>>2)&1; b[6]=(mm>>1)&1; b[7]=mm&1;     // local wires
    float phi = 0.f;
    #pragma unroll
    for (int i = 0; i < 8; ++i)
      phi += b[i] ? (b[(i+1)&7] ? h[i] : -h[i]) : 0.f;
    float c, s; __sincosf(phi, &s, &c);
    phi2[(l*16 + rr)*18 + mm] = {c, s};
  }

  // ------ phase-1 chains: WAVE-LOCAL — wave handles its 4 samples ----------
  #pragma unroll
  for (int k = 0; k < 4; ++k){
    const int s_ = wv*4 + k;                // local sample
    const int p = ln >> 2, q = ln & 3;      // 16 patches x 4 wires = 64 lanes
    const int pi = p >> 2, pj = p & 3;
    const int shift = (pj == 3) ? 1 : 2;
    const int cmask = (1 << shift) - 1;
    const int limit = ((pi == 3) ? 2 : 4) << shift;
    int gs = blockIdx.x * 16 + s_;
    if (gs >= bs) gs = bs - 1;
    const float* Xf = X + (size_t)gs * 196;  // L1/L2-resident
    float ang[4];
    #pragma unroll
    for (int i = 0; i < 4; ++i){
      const int k2 = q*4 + i;
      int idx = (pi*4 + (k2 >> shift))*14 + pj*4 + (k2 & cmask);
      idx = idx > 195 ? 195 : idx;
      float v = Xf[idx];
      ang[i] = (k2 < limit) ? v : 0.f;      // RZ(0)/RX(0) == identity
    }
    f32x2 v[2];
    build_psi<4>(v, ang, 1.0f);
    p1chain[s_][p][q] = {v[0].x, v[0].y, v[1].x, v[1].y};
  }
  __syncthreads();                          // the ONLY barrier (tables + chains)

  // ------- phase 1 evolution: patch r per lane, all 4 wires LOCAL ----------
  {
    f32x2 ps[4][2];
    #pragma unroll
    for (int q = 0; q < 4; ++q){
      float4 fq = p1chain[sl][r][q];
      ps[q][0].x = fq.x; ps[q][0].y = fq.y;
      ps[q][1].x = fq.z; ps[q][1].y = fq.w;
    }
    f32x2 a[16];
    {
      f32x2 T01[4], T23[4];
      #pragma unroll
      for (int j = 0; j < 4; ++j){
        T01[j] = cmulv(ps[0][j>>1], ps[1][j&1]);
        T23[j] = cmulv(ps[2][j>>1], ps[3][j&1]);
      }
      #pragma unroll
      for (int m = 0; m < 16; ++m) a[m] = cmulv(T01[m>>2], T23[m&3]);
    }

    #pragma unroll
    for (int l = 0; l < 2; ++l){
      const float4* ph4 = (const float4*)&p1phi2[l][0];  // uniform broadcast
      #pragma unroll
      for (int j = 0; j < 8; ++j){
        float4 w = ph4[j];
        a[2*j]   = cphase2(a[2*j],   w.x, w.y);
        a[2*j+1] = cphase2(a[2*j+1], w.z, w.w);
      }
      ry_loc16<8>(a, p1ry[l][0]); ry_loc16<4>(a, p1ry[l][1]);
      ry_loc16<2>(a, p1ry[l][2]); ry_loc16<1>(a, p1ry[l][3]);
    }

    float pr[16];
    #pragma unroll
    for (int m = 0; m < 16; ++m) pr[m] = a[m].x*a[m].x + a[m].y*a[m].y;
    #pragma unroll
    for (int w = 0; w < 4; ++w){
      const int S = 8 >> w;
      float e = 0.f;
      #pragma unroll
      for (int m = 0; m < 16; ++m) e += (m & S) ? -pr[m] : pr[m];
      feats[sl][r*4 + w] = e;
    }
    feats[sl][64 + r] = 0.f;                // zero pad f[64..79]
  }
  wave_lds_fence();                         // wave-local: no barrier

  // ------ phase-2 chains: WAVE-LOCAL, full chains on lanes 0..31 -----------
  if (ln < 32){
    const int s_ = wv*4 + (ln >> 3), c = ln & 7;
    f32x2 v[2];
    build_psi<9>(v, &feats[s_][c*9], PI_F);
    chain2[s_][c] = {v[0].x, v[0].y, v[1].x, v[1].y};
  }
  wave_lds_fence();                         // wave-local: no barrier

  // ------- assemble product state: lanes = wires 0-3, local = wires 4-7 ----
  f32x2 a[16];
  {
    const float2* c2 = (const float2*)&chain2[sl][0];
    f32x2 e0 = tov(c2[0*2 + ((r>>3)&1)]);
    f32x2 e1 = tov(c2[1*2 + ((r>>2)&1)]);
    f32x2 e2 = tov(c2[2*2 + ((r>>1)&1)]);
    f32x2 e3 = tov(c2[3*2 + ( r    &1)]);
    f32x2 L  = cmulv(cmulv(e0, e1), cmulv(e2, e3));

    float4 q4 = chain2[sl][4], q5 = chain2[sl][5];
    float4 q6 = chain2[sl][6], q7 = chain2[sl][7];
    f32x2 p4[2], p5[2], p6[2], p7[2];
    p4[0].x=q4.x; p4[0].y=q4.y; p4[1].x=q4.z; p4[1].y=q4.w;
    p5[0].x=q5.x; p5[0].y=q5.y; p5[1].x=q5.z; p5[1].y=q5.w;
    p6[0].x=q6.x; p6[0].y=q6.y; p6[1].x=q6.z; p6[1].y=q6.w;
    p7[0].x=q7.x; p7[0].y=q7.y; p7[1].x=q7.z; p7[1].y=q7.w;
    f32x2 p45[4], p67[4];
    #pragma unroll
    for (int j = 0; j < 4; ++j){
      p45[j] = cmulv(p4[j>>1], p5[j&1]);
      p67[j] = cmulv(p6[j>>1], p7[j&1]);
    }
    f32x2 Lp[4];
    #pragma unroll
    for (int j = 0; j < 4; ++j) Lp[j] = cmulv(L, p45[j]);
    #pragma unroll
    for (int m = 0; m < 16; ++m) a[m] = cmulv(Lp[m>>2], p67[m&3]);
  }

  // ---------------- 3 layers: table-CRZ ring + RY on wires 0..7 ------------
  #pragma unroll
  for (int l = 0; l < 3; ++l){
    const float4* ph4 = (const float4*)&phi2[(l*16 + r)*18];
    #pragma unroll
    for (int j = 0; j < 8; ++j){
      float4 w = ph4[j];
      a[2*j]   = cphase2(a[2*j],   w.x, w.y);
      a[2*j+1] = cphase2(a[2*j+1], w.z, w.w);
    }
    ry_lane16<8>(a, r, ryw[l][0]);          // wire0 (DPP row_ror:8)
    ry_lane16<4>(a, r, ryw[l][1]);          // wire1 (ds_swizzle — the only one)
    ry_lane16<2>(a, r, ryw[l][2]);          // wire2 (DPP quad)
    ry_lane16<1>(a, r, ryw[l][3]);          // wire3 (DPP quad)
    ry_loc16<8>(a, ryw[l][4]);              // wire4
    ry_loc16<4>(a, ryw[l][5]);              // wire5
    ry_loc16<2>(a, ryw[l][6]);              // wire6
    ry_loc16<1>(a, ryw[l][7]);              // wire7
  }

  // ---------------- measurement + FC ---------------------------------------
  float pr[16];
  #pragma unroll
  for (int m = 0; m < 16; ++m) pr[m] = a[m].x*a[m].x + a[m].y*a[m].y;
  float Ssum = 0.f;
  #pragma unroll
  for (int m = 0; m < 16; ++m) Ssum += pr[m];
  float gp[8];
  gp[0] = (r & 8) ? -Ssum : Ssum;
  gp[1] = (r & 4) ? -Ssum : Ssum;
  gp[2] = (r & 2) ? -Ssum : Ssum;
  gp[3] = (r & 1) ? -Ssum : Ssum;
  #pragma unroll
  for (int w = 4; w < 8; ++w){
    const int S = 8 >> (w-4);
    float e = 0.f;
    #pragma unroll
    for (int m = 0; m < 16; ++m) e += (m & S) ? -pr[m] : pr[m];
    gp[w] = e;
  }

  float o0 = 0.f, o1 = 0.f, o2 = 0.f;
  #pragma unroll
  for (int w = 0; w < 8; ++w){
    o0 += fcw[0*8 + w] * gp[w];
    o1 += fcw[1*8 + w] * gp[w];
    o2 += fcw[2*8 + w] * gp[w];
  }
  o0 += shfx<1>(o0); o1 += shfx<1>(o1); o2 += shfx<1>(o2);
  o0 += shfx<2>(o0); o1 += shfx<2>(o1); o2 += shfx<2>(o2);
  o0 += shfx<4>(o0); o1 += shfx<4>(o1); o2 += shfx<4>(o2);
  o0 += shfx<8>(o0); o1 += shfx<8>(o1); o2 += shfx<8>(o2);

  if (r < 3){
    float o = (r == 0) ? o0 : ((r == 1) ? o1 : o2);
    out[(size_t)sample*3 + r] = o + fcb[r];
  }
}

extern "C" void kernel_launch(void* const* d_in, const int* in_sizes, int n_in,
                              void* d_out, int out_size, void* d_ws, size_t ws_size,
                              hipStream_t stream)
{
  const float* X   = (const float*)d_in[0];
  const float* w1  = (const float*)d_in[1];
  const float* w2  = (const float*)d_in[2];
  const float* fcw = (const float*)d_in[3];
  const float* fcb = (const float*)d_in[4];
  float* out = (float*)d_out;
  const int bs = in_sizes[0] / 196;            // 8192
  const int blocks = (bs + 15) / 16;           // 16 samples / 256-thread block
  hipLaunchKernelGGL(qnn_fused_kernel, dim3(blocks), dim3(256), 0, stream,
                     X, w1, w2, fcw, fcb, out, bs);
}